// Round 1
// baseline (4056.504 us; speedup 1.0000x reference)
//
#include <hip/hip_runtime.h>

#define D 512
#define C 1024
#define TILE_P 64
#define TILE_C 128
#define KC 32

// One wave per code: ||c||^2
__global__ __launch_bounds__(256) void cbnorm_kernel(const float* __restrict__ cb,
                                                     float* __restrict__ cbn) {
    int code = blockIdx.x * 4 + (threadIdx.x >> 6);
    int lane = threadIdx.x & 63;
    const float* row = cb + (size_t)code * D;
    float4 a = *(const float4*)(row + lane * 8);
    float4 b = *(const float4*)(row + lane * 8 + 4);
    float s = a.x*a.x + a.y*a.y + a.z*a.z + a.w*a.w
            + b.x*b.x + b.y*b.y + b.z*b.z + b.w*b.w;
    #pragma unroll
    for (int off = 32; off > 0; off >>= 1) s += __shfl_down(s, off, 64);
    if (lane == 0) cbn[code] = s;
}

// One step of residual VQ: distances + argmin + residual update + loss sum.
// Block: 256 threads (16x16), tile = 64 points x all 1024 codes (chunks of 128).
__global__ __launch_bounds__(256) void vq_step_kernel(
    const float* __restrict__ rin,      // residual in (x when q==0)
    float*       __restrict__ rout,     // residual out (in-place region of d_out)
    const float* __restrict__ cb,       // [C][D] codebook for this step
    const float* __restrict__ cbn,      // [C] code norms
    float*       __restrict__ idx_out,  // indices region, write at p*nq + q (as float)
    float*       __restrict__ loss_accum, // raw sum of new_residual^2
    int q, int nq)
{
    __shared__ float As[KC][TILE_P + 4];
    __shared__ float Bs[KC][TILE_C + 4];
    __shared__ float redS[TILE_P][16];
    __shared__ int   redI[TILE_P][16];
    __shared__ int   finalIdx[TILE_P];
    __shared__ float wsum[4];

    const int tid = threadIdx.x;
    const int tx = tid & 15;
    const int ty = tid >> 4;
    const int bp = blockIdx.x * TILE_P;

    float best[4];
    int bidx[4];
    #pragma unroll
    for (int i = 0; i < 4; ++i) { best[i] = 3.4e38f; bidx[i] = 0; }

    for (int cc = 0; cc < C; cc += TILE_C) {
        float acc[4][8];
        #pragma unroll
        for (int i = 0; i < 4; ++i)
            #pragma unroll
            for (int j = 0; j < 8; ++j) acc[i][j] = 0.f;

        for (int k0 = 0; k0 < D; k0 += KC) {
            __syncthreads();
            // stage A tile: 64 pts x 32 k (transposed to [k][p])
            #pragma unroll
            for (int it = 0; it < 2; ++it) {
                int i = tid + it * 256;
                int p = i >> 3;
                int kq = (i & 7) * 4;
                float4 v = *(const float4*)(rin + (size_t)(bp + p) * D + k0 + kq);
                As[kq + 0][p] = v.x;
                As[kq + 1][p] = v.y;
                As[kq + 2][p] = v.z;
                As[kq + 3][p] = v.w;
            }
            // stage B tile: 128 codes x 32 k (transposed to [k][c])
            #pragma unroll
            for (int it = 0; it < 4; ++it) {
                int i = tid + it * 256;
                int c = i >> 3;
                int kq = (i & 7) * 4;
                float4 v = *(const float4*)(cb + (size_t)(cc + c) * D + k0 + kq);
                Bs[kq + 0][c] = v.x;
                Bs[kq + 1][c] = v.y;
                Bs[kq + 2][c] = v.z;
                Bs[kq + 3][c] = v.w;
            }
            __syncthreads();
            #pragma unroll
            for (int k = 0; k < KC; ++k) {
                float4 a  = *(const float4*)&As[k][ty * 4];
                float4 b0 = *(const float4*)&Bs[k][tx * 8];
                float4 b1 = *(const float4*)&Bs[k][tx * 8 + 4];
                float av[4] = {a.x, a.y, a.z, a.w};
                float bv[8] = {b0.x, b0.y, b0.z, b0.w, b1.x, b1.y, b1.z, b1.w};
                #pragma unroll
                for (int i = 0; i < 4; ++i)
                    #pragma unroll
                    for (int j = 0; j < 8; ++j)
                        acc[i][j] = fmaf(av[i], bv[j], acc[i][j]);
            }
        }
        // fold chunk into running argmin (ascending code order, strict < => first-index ties)
        #pragma unroll
        for (int j = 0; j < 8; ++j) {
            int code = cc + tx * 8 + j;
            float nrm = cbn[code];
            #pragma unroll
            for (int i = 0; i < 4; ++i) {
                float score = fmaf(-2.f, acc[i][j], nrm);
                if (score < best[i]) { best[i] = score; bidx[i] = code; }
            }
        }
    }

    __syncthreads();
    #pragma unroll
    for (int i = 0; i < 4; ++i) {
        redS[ty * 4 + i][tx] = best[i];
        redI[ty * 4 + i][tx] = bidx[i];
    }
    __syncthreads();
    if (tid < TILE_P) {
        float bs = redS[tid][0];
        int bi = redI[tid][0];
        #pragma unroll
        for (int t = 1; t < 16; ++t) {
            float s = redS[tid][t];
            int ix = redI[tid][t];
            if (s < bs || (s == bs && ix < bi)) { bs = s; bi = ix; }
        }
        finalIdx[tid] = bi;
        idx_out[(size_t)(bp + tid) * nq + q] = (float)bi;
    }
    __syncthreads();

    // update residual in place, accumulate sum((c - r)^2) = sum(new_r^2)
    float lsum = 0.f;
    for (int pp = 0; pp < TILE_P; pp += 2) {
        int p = pp + (tid >> 7);
        int e = (tid & 127) * 4;
        int ci = finalIdx[p];
        float4 rv = *(const float4*)(rin + (size_t)(bp + p) * D + e);
        float4 cv = *(const float4*)(cb + (size_t)ci * D + e);
        float4 nv;
        nv.x = rv.x - cv.x;
        nv.y = rv.y - cv.y;
        nv.z = rv.z - cv.z;
        nv.w = rv.w - cv.w;
        *(float4*)(rout + (size_t)(bp + p) * D + e) = nv;
        lsum = fmaf(nv.x, nv.x, lsum);
        lsum = fmaf(nv.y, nv.y, lsum);
        lsum = fmaf(nv.z, nv.z, lsum);
        lsum = fmaf(nv.w, nv.w, lsum);
    }
    #pragma unroll
    for (int off = 32; off > 0; off >>= 1) lsum += __shfl_down(lsum, off, 64);
    if ((tid & 63) == 0) wsum[tid >> 6] = lsum;
    __syncthreads();
    if (tid == 0) atomicAdd(loss_accum, wsum[0] + wsum[1] + wsum[2] + wsum[3]);
}

// quantized = x - final_residual (in place); scale losses.
__global__ __launch_bounds__(256) void finalize_kernel(
    const float* __restrict__ x, float* __restrict__ outq,
    float* __restrict__ losses, float invPD, int n4, int nq)
{
    int stride = gridDim.x * blockDim.x;
    for (int i = blockIdx.x * blockDim.x + threadIdx.x; i < n4; i += stride) {
        float4 xv = ((const float4*)x)[i];
        float4 rv = ((float4*)outq)[i];
        float4 qv;
        qv.x = xv.x - rv.x;
        qv.y = xv.y - rv.y;
        qv.z = xv.z - rv.z;
        qv.w = xv.w - rv.w;
        ((float4*)outq)[i] = qv;
    }
    if (blockIdx.x == 0 && threadIdx.x < nq) {
        float vq = losses[threadIdx.x] * invPD;
        losses[threadIdx.x] = vq;
        losses[nq + threadIdx.x] = 0.25f * vq;
    }
}

extern "C" void kernel_launch(void* const* d_in, const int* in_sizes, int n_in,
                              void* d_out, int out_size, void* d_ws, size_t ws_size,
                              hipStream_t stream)
{
    const float* x   = (const float*)d_in[0];  // [B,N,D] fp32
    const float* cbs = (const float*)d_in[1];  // [Q,C,D] fp32
    const int PD = in_sizes[0];                // B*N*D = 16777216
    const int P  = PD / D;                     // 32768 points
    const int nq = in_sizes[1] / (C * D);      // 8

    float* out     = (float*)d_out;
    float* resid   = out;                       // residual lives in quantized region
    float* idx_out = out + (size_t)PD;          // [P][nq] indices as float
    float* losses  = idx_out + (size_t)P * nq;  // vq[nq] then qq[nq]
    float* cbn     = (float*)d_ws;              // nq*C floats (32 KB)

    hipMemsetAsync(losses, 0, sizeof(float) * 2 * nq, stream);
    cbnorm_kernel<<<nq * C / 4, 256, 0, stream>>>(cbs, cbn);
    for (int q = 0; q < nq; ++q) {
        vq_step_kernel<<<P / TILE_P, 256, 0, stream>>>(
            q == 0 ? x : resid, resid,
            cbs + (size_t)q * C * D, cbn + (size_t)q * C,
            idx_out, losses + q, q, nq);
    }
    finalize_kernel<<<2048, 256, 0, stream>>>(x, out, losses, 1.f / (float)PD, PD / 4, nq);
}